// Round 7
// baseline (1361.590 us; speedup 1.0000x reference)
//
#include <hip/hip_runtime.h>
#include <cstdint>
#include <cstddef>

#define NN 100000
#define BN_EPS 1e-5f

typedef __attribute__((ext_vector_type(8))) short short8;
typedef __attribute__((ext_vector_type(4))) float f32x4;

static __device__ __forceinline__ float bflo(unsigned u){ return __uint_as_float(u<<16); }
static __device__ __forceinline__ float bfhi(unsigned u){ return __uint_as_float(u & 0xFFFF0000u); }
static __device__ __forceinline__ unsigned short f2bf(float f){
  unsigned u = __float_as_uint(f);
  u += 0x7FFFu + ((u>>16)&1u);   // round-to-nearest-even
  return (unsigned short)(u>>16);
}

// ---------------- graph prep ----------------

__global__ void k_hist(const int* __restrict__ dst, int* __restrict__ cnt, int E){
  int e = blockIdx.x*blockDim.x + threadIdx.x;
  if(e<E) atomicAdd(&cnt[dst[e]], 1);
}

// norm over N+1: norm[NN] = 0 (zero row / pad-edge killer)
__global__ void k_norm(const int* __restrict__ cnt, float* __restrict__ norm, int n){
  int i = blockIdx.x*blockDim.x + threadIdx.x;
  if(i<=n) norm[i] = (i==n) ? 0.f : rsqrtf(fmaxf((float)cnt[i], 1.0f));
}

// exclusive scan over counts padded to multiple of 8
__global__ __launch_bounds__(1024) void k_scan(const int* __restrict__ cnt, int* __restrict__ rp, int n){
  __shared__ int sm[1024];
  int t = threadIdx.x;
  int chunk = (n + 1023)/1024;
  int lo = t*chunk, hi = min(lo+chunk, n);
  int s=0;
  for(int i=lo;i<hi;i++) s += (cnt[i]+7)&~7;
  sm[t]=s; __syncthreads();
  for(int off=1; off<1024; off<<=1){
    int v = (t>=off)? sm[t-off] : 0;
    __syncthreads();
    sm[t]+=v;
    __syncthreads();
  }
  int run = sm[t]-s;
  for(int i=lo;i<hi;i++){ rp[i]=run; run+=(cnt[i]+7)&~7; }
  if(t==1023) rp[n]=sm[1023];
}

__global__ void k_scatter(const int* __restrict__ src, const int* __restrict__ dst,
                          const int* __restrict__ rp, int* __restrict__ fill,
                          int* __restrict__ esrc, int E){
  int e = blockIdx.x*blockDim.x + threadIdx.x;
  if(e<E){
    int d = dst[e];
    int pos = rp[d] + atomicAdd(&fill[d], 1);
    esrc[pos] = src[e];
  }
}

// sort each node's adjacency ascending (128-wide bitonic, one wave per node)
// and write pad slots = NN. Sorted lists make concurrent agg waves sweep the
// gather table in sync -> L2-resident moving window. Pads (NN > all srcs)
// plus 0x7FFFFFFF sentinels sort to the tail.
__global__ __launch_bounds__(64) void k_sortadj(const int* __restrict__ cnt,
    const int* __restrict__ rp, int* __restrict__ esrc){
  __shared__ int sm[128];
  int node = blockIdx.x;
  int s0 = rp[node], s1 = rp[node+1];
  int len = s1 - s0;               // padded, multiple of 8
  int c = cnt[node];
  int t = threadIdx.x;
  if(len == 0) return;
  if(len > 128){                   // rare fallback: pads only, no sort
    for(int i = c + t; i < len; i += 64) esrc[s0+i] = NN;
    return;
  }
  sm[t]    = (t    < c) ? esrc[s0+t]    : 0x7FFFFFFF;
  sm[t+64] = (t+64 < c) ? esrc[s0+t+64] : 0x7FFFFFFF;
  __syncthreads();
  for(int k=2; k<=128; k<<=1){
    for(int j=k>>1; j>0; j>>=1){
      #pragma unroll
      for(int h=0; h<2; h++){
        int i = t + h*64;
        int l = i ^ j;
        if(l > i){
          int vi = sm[i], vl = sm[l];
          bool up = ((i & k) == 0);
          if((vi > vl) == up){ sm[i]=vl; sm[l]=vi; }
        }
      }
      __syncthreads();
    }
  }
  if(t < len)    esrc[s0+t]    = (t    < c) ? sm[t]    : NN;
  if(t+64 < len) esrc[s0+t+64] = (t+64 < c) ? sm[t+64] : NN;
}

// zero pad rows: Hx row NN (128), X3p row NN (64), Z row NN (256)
__global__ void k_zeropad(unsigned short* __restrict__ Hx, unsigned short* __restrict__ X3p,
                          unsigned short* __restrict__ Z){
  int t = threadIdx.x;
  if(t<128) Hx[(size_t)NN*128 + t] = 0;
  if(t<64)  X3p[(size_t)NN*64 + t] = 0;
  Z[(size_t)NN*256 + t] = 0;
}

// ---------------- elementwise / weight prep ----------------

__global__ void k_scale_x(const float* __restrict__ x, const float* __restrict__ norm,
                          unsigned short* __restrict__ H, int total){
  int i = blockIdx.x*blockDim.x + threadIdx.x;
  if(i<total) H[i] = f2bf(x[i] * norm[i>>7]);   // 128 feats/row
}

// W (K x N fp32) -> Wt (N x K bf16)
__global__ void k_wprep(const float* __restrict__ W, unsigned short* __restrict__ Wt, int K, int N){
  int i = blockIdx.x*blockDim.x + threadIdx.x;
  if(i < K*N){
    int k = i / N, n = i - k*N;
    Wt[(size_t)n*K + k] = f2bf(W[i]);
  }
}

// W3 (256 x 40 fp32) -> Wt3 (64 x 256 bf16), rows >= 40 zero
__global__ void k_wprep3(const float* __restrict__ W3, unsigned short* __restrict__ Wt){
  int i = blockIdx.x*blockDim.x + threadIdx.x;
  if(i < 64*256){
    int n = i >> 8, k = i & 255;
    Wt[i] = (n < 40) ? f2bf(W3[(size_t)k*40 + n]) : (unsigned short)0;
  }
}

// ---------------- BN stats ----------------

__global__ __launch_bounds__(256) void k_colstats(const unsigned short* __restrict__ Z,
    float* __restrict__ sums, int M){
  int c = threadIdx.x;
  float s=0.f, s2=0.f;
  for(int r=blockIdx.x; r<M; r+=gridDim.x){
    float v = bflo((unsigned)Z[(size_t)r*256 + c]);
    s+=v; s2+=v*v;
  }
  atomicAdd(&sums[c], s);
  atomicAdd(&sums[256+c], s2);
}

__global__ void k_bnfin(const float* __restrict__ sums, const float* __restrict__ gamma,
                        const float* __restrict__ beta, float* __restrict__ scsh, int M){
  int c = threadIdx.x;
  float mean = sums[c]/(float)M;
  float var  = sums[256+c]/(float)M - mean*mean;
  float sc = gamma[c]*rsqrtf(var + BN_EPS);
  scsh[c] = sc;
  scsh[256+c] = beta[c] - mean*sc;
}

// BN+ReLU for layer-3 input: Z bf16 -> H bf16
__global__ void k_bnrelu2(const unsigned short* __restrict__ Z, const float* __restrict__ scsh,
                          unsigned short* __restrict__ H, int total){
  int i = blockIdx.x*blockDim.x + threadIdx.x;
  if(i<total){
    int c = i & 255;
    H[i] = f2bf(fmaxf(bflo((unsigned)Z[i])*scsh[c] + scsh[256+c], 0.f));
  }
}

// ---------------- aggregation (wave per node, padded+sorted CSR) ----------------

__global__ __launch_bounds__(64) void k_agg128(const unsigned short* __restrict__ H,
    const int* __restrict__ rp, const int* __restrict__ esrc,
    const float* __restrict__ norm, unsigned short* __restrict__ out){
  int node = blockIdx.x, lane = threadIdx.x;
  int s0 = rp[node], s1 = rp[node+1];
  float a0=0.f, a1=0.f;
  for(int e=s0; e<s1; e+=4){
    int4 cur = *(const int4*)(esrc+e);
    unsigned v0 = *(const unsigned*)(H + (size_t)cur.x*128 + lane*2);
    unsigned v1 = *(const unsigned*)(H + (size_t)cur.y*128 + lane*2);
    unsigned v2 = *(const unsigned*)(H + (size_t)cur.z*128 + lane*2);
    unsigned v3 = *(const unsigned*)(H + (size_t)cur.w*128 + lane*2);
    a0 += bflo(v0)+bflo(v1)+bflo(v2)+bflo(v3);
    a1 += bfhi(v0)+bfhi(v1)+bfhi(v2)+bfhi(v3);
  }
  float nn = norm[node];
  unsigned pk = (unsigned)f2bf(a0*nn) | ((unsigned)f2bf(a1*nn) << 16);
  *(unsigned*)(out + (size_t)node*128 + lane*2) = pk;
}

// layer-2 aggregation with BN+ReLU+norm[src] fused into the gather.
// reads raw Z1 (bf16, pre-BN, has zero row NN); lane owns cols lane*4..lane*4+3.
__global__ __launch_bounds__(64) void k_agg256f(const unsigned short* __restrict__ Z,
    const int* __restrict__ rp, const int* __restrict__ esrc,
    const float* __restrict__ norm, const float* __restrict__ scsh,
    unsigned short* __restrict__ out){
  int node = blockIdx.x, lane = threadIdx.x;
  float4 sc = *(const float4*)(scsh + lane*4);
  float4 sh = *(const float4*)(scsh + 256 + lane*4);
  int s0 = rp[node], s1 = rp[node+1];
  float a0=0.f,a1=0.f,a2=0.f,a3=0.f;
  for(int e=s0; e<s1; e+=4){
    int4 cur = *(const int4*)(esrc+e);
    float n0=norm[cur.x], n1=norm[cur.y], n2=norm[cur.z], n3=norm[cur.w];
    uint2 va = *(const uint2*)(Z + (size_t)cur.x*256 + lane*4);
    uint2 vb = *(const uint2*)(Z + (size_t)cur.y*256 + lane*4);
    uint2 vc = *(const uint2*)(Z + (size_t)cur.z*256 + lane*4);
    uint2 vd = *(const uint2*)(Z + (size_t)cur.w*256 + lane*4);
    a0 += fmaxf(bflo(va.x)*sc.x+sh.x,0.f)*n0 + fmaxf(bflo(vb.x)*sc.x+sh.x,0.f)*n1
        + fmaxf(bflo(vc.x)*sc.x+sh.x,0.f)*n2 + fmaxf(bflo(vd.x)*sc.x+sh.x,0.f)*n3;
    a1 += fmaxf(bfhi(va.x)*sc.y+sh.y,0.f)*n0 + fmaxf(bfhi(vb.x)*sc.y+sh.y,0.f)*n1
        + fmaxf(bfhi(vc.x)*sc.y+sh.y,0.f)*n2 + fmaxf(bfhi(vd.x)*sc.y+sh.y,0.f)*n3;
    a2 += fmaxf(bflo(va.y)*sc.z+sh.z,0.f)*n0 + fmaxf(bflo(vb.y)*sc.z+sh.z,0.f)*n1
        + fmaxf(bflo(vc.y)*sc.z+sh.z,0.f)*n2 + fmaxf(bflo(vd.y)*sc.z+sh.z,0.f)*n3;
    a3 += fmaxf(bfhi(va.y)*sc.w+sh.w,0.f)*n0 + fmaxf(bfhi(vb.y)*sc.w+sh.w,0.f)*n1
        + fmaxf(bfhi(vc.y)*sc.w+sh.w,0.f)*n2 + fmaxf(bfhi(vd.y)*sc.w+sh.w,0.f)*n3;
  }
  float nn = norm[node];
  uint2 pk;
  pk.x = (unsigned)f2bf(a0*nn) | ((unsigned)f2bf(a1*nn) << 16);
  pk.y = (unsigned)f2bf(a2*nn) | ((unsigned)f2bf(a3*nn) << 16);
  *(uint2*)(out + (size_t)node*256 + lane*4) = pk;
}

// final aggregation: X3p rows 64 bf16 (cols 40-63 zero). 8 edges/iter, uint4/lane.
__global__ __launch_bounds__(64) void k_agg64(const unsigned short* __restrict__ X3p,
    const int* __restrict__ rp, const int* __restrict__ esrc,
    const float* __restrict__ norm, const float* __restrict__ b3,
    float* __restrict__ out){
  int node = blockIdx.x, lane = threadIdx.x;
  int s0 = rp[node], s1 = rp[node+1];
  int es = lane >> 3, s = lane & 7;
  float a[8] = {};
  for(int e=s0; e<s1; e+=8){
    int4 A4 = *(const int4*)(esrc+e);
    int4 B4 = *(const int4*)(esrc+e+4);
    int idx = es==0?A4.x: es==1?A4.y: es==2?A4.z: es==3?A4.w:
              es==4?B4.x: es==5?B4.y: es==6?B4.z: B4.w;
    uint4 v = *(const uint4*)(X3p + (size_t)idx*64 + s*8);
    a[0]+=bflo(v.x); a[1]+=bfhi(v.x); a[2]+=bflo(v.y); a[3]+=bfhi(v.y);
    a[4]+=bflo(v.z); a[5]+=bfhi(v.z); a[6]+=bflo(v.w); a[7]+=bfhi(v.w);
  }
  #pragma unroll
  for(int off=8; off<64; off<<=1){
    #pragma unroll
    for(int j=0;j<8;j++) a[j] += __shfl_xor(a[j], off, 64);
  }
  bool act = s < 5;   // cols s*8..s*8+7 < 40
  float nn = norm[node];
  float bv[8] = {};
  if(act){
    float4 t0 = *(const float4*)(b3 + s*8);
    float4 t1 = *(const float4*)(b3 + s*8 + 4);
    bv[0]=t0.x; bv[1]=t0.y; bv[2]=t0.z; bv[3]=t0.w;
    bv[4]=t1.x; bv[5]=t1.y; bv[6]=t1.z; bv[7]=t1.w;
  }
  float v[8];
  float mx = -INFINITY;
  #pragma unroll
  for(int j=0;j<8;j++){
    v[j] = act ? (a[j]*nn + bv[j]) : -INFINITY;
    mx = fmaxf(mx, v[j]);
  }
  #pragma unroll
  for(int off=32; off; off>>=1) mx = fmaxf(mx, __shfl_xor(mx, off, 64));
  float sum = 0.f;
  if(act && es==0){
    #pragma unroll
    for(int j=0;j<8;j++) sum += expf(v[j]-mx);
  }
  #pragma unroll
  for(int off=32; off; off>>=1) sum += __shfl_xor(sum, off, 64);
  float lse = logf(sum);
  if(act && es==0){
    float4 o0, o1;
    o0.x=v[0]-mx-lse; o0.y=v[1]-mx-lse; o0.z=v[2]-mx-lse; o0.w=v[3]-mx-lse;
    o1.x=v[4]-mx-lse; o1.y=v[5]-mx-lse; o1.z=v[6]-mx-lse; o1.w=v[7]-mx-lse;
    *(float4*)(out + (size_t)node*40 + s*8) = o0;
    *(float4*)(out + (size_t)node*40 + s*8 + 4) = o1;
  }
}

// ---------------- MFMA GEMM: C[M,N](bf16) = A[M,K](bf16) * Bt[N,K]^T + bias ----------------

__global__ __launch_bounds__(256) void k_mgemm(
    const unsigned short* __restrict__ A, const unsigned short* __restrict__ Bt,
    const float* __restrict__ bias, unsigned short* __restrict__ C, int M, int K, int Nn){
  __shared__ unsigned short As[128*64];
  __shared__ unsigned short Bs[128*64];
  int nt = Nn >> 7;
  int bm = blockIdx.x / nt, bn = blockIdx.x % nt;
  int m0 = bm*128, n0 = bn*128;
  int tid = threadIdx.x;
  int wave = tid >> 6, lane = tid & 63;
  int wm = (wave>>1)*64, wn = (wave&1)*64;
  int lrow = lane & 15, lq = lane >> 4;
  int srow = lane >> 3;
  int sx = ((lane & 7) ^ srow) * 8;
  f32x4 acc[4][4] = {};
  for(int k0=0; k0<K; k0+=64){
    __syncthreads();
    #pragma unroll
    for(int c4=0;c4<4;c4++){
      int c = wave*4 + c4;
      int grow = c*8 + srow;
      const unsigned short* ga = A + (size_t)(m0+grow)*K + k0 + sx;
      __builtin_amdgcn_global_load_lds((const __attribute__((address_space(1))) void*)ga,
          (__attribute__((address_space(3))) void*)(As + (size_t)c*512), 16, 0, 0);
      const unsigned short* gb = Bt + (size_t)(n0+grow)*K + k0 + sx;
      __builtin_amdgcn_global_load_lds((const __attribute__((address_space(1))) void*)gb,
          (__attribute__((address_space(3))) void*)(Bs + (size_t)c*512), 16, 0, 0);
    }
    __syncthreads();
    #pragma unroll
    for(int kk=0;kk<2;kk++){
      short8 af[4], bf[4];
      #pragma unroll
      for(int i=0;i<4;i++){
        int Ra = wm + i*16 + lrow;
        int ca = (kk*4 + lq) ^ (Ra & 7);
        af[i] = *(const short8*)(As + Ra*64 + ca*8);
        int Rb = wn + i*16 + lrow;
        int cb = (kk*4 + lq) ^ (Rb & 7);
        bf[i] = *(const short8*)(Bs + Rb*64 + cb*8);
      }
      #pragma unroll
      for(int i=0;i<4;i++)
        #pragma unroll
        for(int j=0;j<4;j++)
          acc[i][j] = __builtin_amdgcn_mfma_f32_16x16x32_bf16(af[i], bf[j], acc[i][j], 0, 0, 0);
    }
  }
  #pragma unroll
  for(int j=0;j<4;j++){
    int col = n0 + wn + j*16 + lrow;
    float bj = bias ? bias[col] : 0.f;
    #pragma unroll
    for(int i=0;i<4;i++){
      #pragma unroll
      for(int r=0;r<4;r++){
        int row = m0 + wm + i*16 + lq*4 + r;
        if(row < M) C[(size_t)row*Nn + col] = f2bf(acc[i][j][r] + bj);
      }
    }
  }
}

// layer-3: 128x64 tile, Bt = Wt3 (64 x K), out X3p bf16 stride 64 (*rownorm)
__global__ __launch_bounds__(256) void k_mgemm3(
    const unsigned short* __restrict__ A, const unsigned short* __restrict__ Bt,
    const float* __restrict__ rownorm, unsigned short* __restrict__ X3p, int M, int K){
  __shared__ unsigned short As[128*64];
  __shared__ unsigned short Bs[64*64];
  int m0 = blockIdx.x*128;
  int tid = threadIdx.x;
  int wave = tid >> 6, lane = tid & 63;
  int wm = wave*32;
  int lrow = lane & 15, lq = lane >> 4;
  int srow = lane >> 3;
  int sx = ((lane & 7) ^ srow) * 8;
  f32x4 acc[2][4] = {};
  for(int k0=0; k0<K; k0+=64){
    __syncthreads();
    #pragma unroll
    for(int c4=0;c4<4;c4++){
      int c = wave*4 + c4;
      int grow = c*8 + srow;
      const unsigned short* ga = A + (size_t)(m0+grow)*K + k0 + sx;
      __builtin_amdgcn_global_load_lds((const __attribute__((address_space(1))) void*)ga,
          (__attribute__((address_space(3))) void*)(As + (size_t)c*512), 16, 0, 0);
    }
    #pragma unroll
    for(int c4=0;c4<2;c4++){
      int c = wave*2 + c4;
      int grow = c*8 + srow;            // 0..63
      const unsigned short* gb = Bt + (size_t)grow*K + k0 + sx;
      __builtin_amdgcn_global_load_lds((const __attribute__((address_space(1))) void*)gb,
          (__attribute__((address_space(3))) void*)(Bs + (size_t)c*512), 16, 0, 0);
    }
    __syncthreads();
    #pragma unroll
    for(int kk=0;kk<2;kk++){
      short8 af[2], bf[4];
      #pragma unroll
      for(int i=0;i<2;i++){
        int Ra = wm + i*16 + lrow;
        int ca = (kk*4 + lq) ^ (Ra & 7);
        af[i] = *(const short8*)(As + Ra*64 + ca*8);
      }
      #pragma unroll
      for(int j=0;j<4;j++){
        int Rb = j*16 + lrow;
        int cb = (kk*4 + lq) ^ (Rb & 7);
        bf[j] = *(const short8*)(Bs + Rb*64 + cb*8);
      }
      #pragma unroll
      for(int i=0;i<2;i++)
        #pragma unroll
        for(int j=0;j<4;j++)
          acc[i][j] = __builtin_amdgcn_mfma_f32_16x16x32_bf16(af[i], bf[j], acc[i][j], 0, 0, 0);
    }
  }
  #pragma unroll
  for(int j=0;j<4;j++){
    int col = j*16 + lrow;
    #pragma unroll
    for(int i=0;i<2;i++){
      #pragma unroll
      for(int r=0;r<4;r++){
        int row = m0 + wm + i*16 + lq*4 + r;
        if(row < M) X3p[(size_t)row*64 + col] = f2bf(acc[i][j][r] * rownorm[row]);
      }
    }
  }
}

// ---------------- launch ----------------

extern "C" void kernel_launch(void* const* d_in, const int* in_sizes, int n_in,
                              void* d_out, int out_size, void* d_ws, size_t ws_size,
                              hipStream_t stream){
  const float* x   = (const float*)d_in[0];
  const int*   src = (const int*)d_in[1];
  const int*   dst = (const int*)d_in[2];
  const float* W1  = (const float*)d_in[3];
  const float* b1  = (const float*)d_in[4];
  const float* g1  = (const float*)d_in[5];
  const float* be1 = (const float*)d_in[6];
  const float* W2  = (const float*)d_in[7];
  const float* b2  = (const float*)d_in[8];
  const float* g2  = (const float*)d_in[9];
  const float* be2 = (const float*)d_in[10];
  const float* W3  = (const float*)d_in[11];
  const float* b3  = (const float*)d_in[12];
  float* out = (float*)d_out;
  const int N = NN;
  const int E = in_sizes[1];

  char* p = (char*)d_ws;
  size_t off = 0;
  auto alloc = [&](size_t bytes)->void*{
    void* r = p + off;
    off += (bytes + 511) & ~(size_t)511;
    return r;
  };
  // Footprint ~183.8 MB — well under the ~229 MB known-good high-water mark.
  // (Crash forensics: 270 MB crash / 219 pass / 229 pass / 235 crash.)
  int*   cnt   = (int*)  alloc((size_t)N*4);
  int*   fill  = (int*)  alloc((size_t)N*4);
  float* sums1 = (float*)alloc(2048);
  float* sums2 = (float*)alloc(2048);
  size_t zero_bytes = off;                       // cnt|fill|sums zeroed each call
  int*   rp    = (int*)  alloc((size_t)(N+1)*4);
  float* norm  = (float*)alloc((size_t)(N+1)*4);
  float* scsh1 = (float*)alloc(2048);
  float* scsh2 = (float*)alloc(2048);
  unsigned short* Wt1 = (unsigned short*)alloc((size_t)256*128*2);
  unsigned short* Wt2 = (unsigned short*)alloc((size_t)256*256*2);
  unsigned short* Wt3 = (unsigned short*)alloc((size_t)64*256*2);
  int*   esrc  = (int*)  alloc((size_t)(E + 7*N + 16)*4);            // pad-8 CSR
  unsigned short* Hx  = (unsigned short*)alloc((size_t)(N+1)*128*2); // x*norm + zero row
  unsigned short* M1  = (unsigned short*)alloc((size_t)N*128*2);     // agg128 out
  unsigned short* Mb2 = (unsigned short*)alloc((size_t)N*256*2);     // agg256f out; later H2
  unsigned short* Z   = (unsigned short*)alloc((size_t)(N+1)*256*2); // mgemm out + zero row
  unsigned short* X3p = (unsigned short*)alloc((size_t)(N+1)*64*2);  // layer-3 proj (64-col)
  unsigned short* H2  = Mb2;   // relu(bn(Z2)) reuses Mb2 (dead after layer-2 mgemm)
  (void)ws_size; (void)n_in; (void)out_size;

  hipMemsetAsync(d_ws, 0, zero_bytes, stream);

  int eb = (E+255)/256;
  k_hist   <<<eb,256,0,stream>>>(dst, cnt, E);
  k_norm   <<<(N+256)/256,256,0,stream>>>(cnt, norm, N);
  k_scan   <<<1,1024,0,stream>>>(cnt, rp, N);
  k_scatter<<<eb,256,0,stream>>>(src, dst, rp, fill, esrc, E);
  k_sortadj<<<N,64,0,stream>>>(cnt, rp, esrc);   // sort adjacency + write pads
  k_zeropad<<<1,256,0,stream>>>(Hx, X3p, Z);
  k_wprep  <<<(128*256+255)/256,256,0,stream>>>(W1, Wt1, 128, 256);
  k_wprep  <<<(256*256+255)/256,256,0,stream>>>(W2, Wt2, 256, 256);
  k_wprep3 <<<(64*256+255)/256,256,0,stream>>>(W3, Wt3);

  // layer 1: Hx = x*norm -> agg128*norm -> MFMA @W1+b1 -> Z1(bf16) -> stats
  k_scale_x<<<(N*128+255)/256,256,0,stream>>>(x, norm, Hx, N*128);
  k_agg128 <<<N,64,0,stream>>>(Hx, rp, esrc, norm, M1);
  k_mgemm  <<<((N+127)/128)*2,256,0,stream>>>(M1, Wt1, b1, Z, N, 128, 256);
  k_colstats<<<512,256,0,stream>>>(Z, sums1, N);
  k_bnfin  <<<1,256,0,stream>>>(sums1, g1, be1, scsh1, N);

  // layer 2: agg256 with fused BN+ReLU+norm[src] reading Z1 -> MFMA @W2+b2 -> Z2 -> stats
  k_agg256f<<<N,64,0,stream>>>(Z, rp, esrc, norm, scsh1, Mb2);
  k_mgemm  <<<((N+127)/128)*2,256,0,stream>>>(Mb2, Wt2, b2, Z, N, 256, 256);
  k_colstats<<<512,256,0,stream>>>(Z, sums2, N);
  k_bnfin  <<<1,256,0,stream>>>(sums2, g2, be2, scsh2, N);
  k_bnrelu2<<<(N*256+255)/256,256,0,stream>>>(Z, scsh2, H2, N*256);

  // layer 3: X3p = (H2 @ W3p)*norm[row] (bf16, 64-col) -> agg64 + b3 -> log_softmax
  k_mgemm3 <<<(N+127)/128,256,0,stream>>>(H2, Wt3, norm, X3p, N, 256);
  k_agg64  <<<N,64,0,stream>>>(X3p, rp, esrc, norm, b3, out);
}

// Round 8
// 1262.813 us; speedup vs baseline: 1.0782x; 1.0782x over previous
//
#include <hip/hip_runtime.h>
#include <cstdint>
#include <cstddef>

#define NN 100000
#define BN_EPS 1e-5f

typedef __attribute__((ext_vector_type(8))) short short8;
typedef __attribute__((ext_vector_type(4))) float f32x4;

static __device__ __forceinline__ float bflo(unsigned u){ return __uint_as_float(u<<16); }
static __device__ __forceinline__ float bfhi(unsigned u){ return __uint_as_float(u & 0xFFFF0000u); }
static __device__ __forceinline__ unsigned short f2bf(float f){
  unsigned u = __float_as_uint(f);
  u += 0x7FFFu + ((u>>16)&1u);   // round-to-nearest-even
  return (unsigned short)(u>>16);
}
static __device__ __forceinline__ unsigned pk2(float a, float b){
  return (unsigned)f2bf(a) | ((unsigned)f2bf(b) << 16);
}

// ---------------- graph prep ----------------

__global__ void k_hist(const int* __restrict__ dst, int* __restrict__ cnt, int E){
  int e = blockIdx.x*blockDim.x + threadIdx.x;
  if(e<E) atomicAdd(&cnt[dst[e]], 1);
}

// norm over N+1: norm[NN] = 0 (zero row / pad-edge killer)
__global__ void k_norm(const int* __restrict__ cnt, float* __restrict__ norm, int n){
  int i = blockIdx.x*blockDim.x + threadIdx.x;
  if(i<=n) norm[i] = (i==n) ? 0.f : rsqrtf(fmaxf((float)cnt[i], 1.0f));
}

// exclusive scan over counts padded to multiple of 8
__global__ __launch_bounds__(1024) void k_scan(const int* __restrict__ cnt, int* __restrict__ rp, int n){
  __shared__ int sm[1024];
  int t = threadIdx.x;
  int chunk = (n + 1023)/1024;
  int lo = t*chunk, hi = min(lo+chunk, n);
  int s=0;
  for(int i=lo;i<hi;i++) s += (cnt[i]+7)&~7;
  sm[t]=s; __syncthreads();
  for(int off=1; off<1024; off<<=1){
    int v = (t>=off)? sm[t-off] : 0;
    __syncthreads();
    sm[t]+=v;
    __syncthreads();
  }
  int run = sm[t]-s;
  for(int i=lo;i<hi;i++){ rp[i]=run; run+=(cnt[i]+7)&~7; }
  if(t==1023) rp[n]=sm[1023];
}

// bidirected structure: src=concat(s,d), dst=concat(d,s). Read only first halves,
// insert both directions. fill[] pre-loaded with rp[] (d2d copy) -> no rp gather.
__global__ void k_scatter2(const int* __restrict__ srch, const int* __restrict__ dsth,
                           int* __restrict__ fill, int* __restrict__ esrc, int Eh){
  int e = blockIdx.x*blockDim.x + threadIdx.x;
  if(e<Eh){
    int s = srch[e], d = dsth[e];
    int p1 = atomicAdd(&fill[d], 1);
    esrc[p1] = s;
    int p2 = atomicAdd(&fill[s], 1);
    esrc[p2] = d;
  }
}

// pad slots [fill[i], rp[i+1]) with NN (fill[i] == rp[i]+cnt[i] after scatter)
__global__ void k_pad(const int* __restrict__ fill, const int* __restrict__ rp,
                      int* __restrict__ esrc, int n){
  int i = blockIdx.x*blockDim.x + threadIdx.x;
  if(i<n){
    int base = fill[i], end = rp[i+1];
    for(int j=base;j<end;j++) esrc[j]=NN;
  }
}

// zero pad rows: Hx row NN (128), X3p row NN (64), Z row NN (256)
__global__ void k_zeropad(unsigned short* __restrict__ Hx, unsigned short* __restrict__ X3p,
                          unsigned short* __restrict__ Z){
  int t = threadIdx.x;
  if(t<128) Hx[(size_t)NN*128 + t] = 0;
  if(t<64)  X3p[(size_t)NN*64 + t] = 0;
  Z[(size_t)NN*256 + t] = 0;
}

// ---------------- elementwise / weight prep ----------------

__global__ void k_scale_x(const float* __restrict__ x, const float* __restrict__ norm,
                          unsigned short* __restrict__ H, int total){
  int i = blockIdx.x*blockDim.x + threadIdx.x;
  if(i<total) H[i] = f2bf(x[i] * norm[i>>7]);   // 128 feats/row
}

// W (K x N fp32) -> Wt (N x K bf16)
__global__ void k_wprep(const float* __restrict__ W, unsigned short* __restrict__ Wt, int K, int N){
  int i = blockIdx.x*blockDim.x + threadIdx.x;
  if(i < K*N){
    int k = i / N, n = i - k*N;
    Wt[(size_t)n*K + k] = f2bf(W[i]);
  }
}

// W3 (256 x 40 fp32) -> Wt3 (64 x 256 bf16), rows >= 40 zero
__global__ void k_wprep3(const float* __restrict__ W3, unsigned short* __restrict__ Wt){
  int i = blockIdx.x*blockDim.x + threadIdx.x;
  if(i < 64*256){
    int n = i >> 8, k = i & 255;
    Wt[i] = (n < 40) ? f2bf(W3[(size_t)k*40 + n]) : (unsigned short)0;
  }
}

// ---------------- BN finalize ----------------

__global__ void k_bnfin(const float* __restrict__ sums, const float* __restrict__ gamma,
                        const float* __restrict__ beta, float* __restrict__ scsh, int M){
  int c = threadIdx.x;
  float mean = sums[c]/(float)M;
  float var  = sums[256+c]/(float)M - mean*mean;
  float sc = gamma[c]*rsqrtf(var + BN_EPS);
  scsh[c] = sc;
  scsh[256+c] = beta[c] - mean*sc;
}

// ---------------- aggregation (wave per node, padded CSR) ----------------

__global__ __launch_bounds__(64) void k_agg128(const unsigned short* __restrict__ H,
    const int* __restrict__ rp, const int* __restrict__ esrc,
    const float* __restrict__ norm, unsigned short* __restrict__ out){
  int node = blockIdx.x, lane = threadIdx.x;
  int s0 = rp[node], s1 = rp[node+1];
  float a0=0.f, a1=0.f;
  for(int e=s0; e<s1; e+=4){
    int4 cur = *(const int4*)(esrc+e);
    unsigned v0 = *(const unsigned*)(H + (size_t)cur.x*128 + lane*2);
    unsigned v1 = *(const unsigned*)(H + (size_t)cur.y*128 + lane*2);
    unsigned v2 = *(const unsigned*)(H + (size_t)cur.z*128 + lane*2);
    unsigned v3 = *(const unsigned*)(H + (size_t)cur.w*128 + lane*2);
    a0 += bflo(v0)+bflo(v1)+bflo(v2)+bflo(v3);
    a1 += bfhi(v0)+bfhi(v1)+bfhi(v2)+bfhi(v3);
  }
  float nn = norm[node];
  *(unsigned*)(out + (size_t)node*128 + lane*2) = pk2(a0*nn, a1*nn);
}

// layer-2 aggregation with BN+ReLU+norm[src] fused into the gather.
// reads raw Z1 (bf16, pre-BN, zero row NN); lane owns cols lane*4..lane*4+3.
__global__ __launch_bounds__(64) void k_agg256f(const unsigned short* __restrict__ Z,
    const int* __restrict__ rp, const int* __restrict__ esrc,
    const float* __restrict__ norm, const float* __restrict__ scsh,
    unsigned short* __restrict__ out){
  int node = blockIdx.x, lane = threadIdx.x;
  float4 sc = *(const float4*)(scsh + lane*4);
  float4 sh = *(const float4*)(scsh + 256 + lane*4);
  int s0 = rp[node], s1 = rp[node+1];
  float a0=0.f,a1=0.f,a2=0.f,a3=0.f;
  for(int e=s0; e<s1; e+=4){
    int4 cur = *(const int4*)(esrc+e);
    float n0=norm[cur.x], n1=norm[cur.y], n2=norm[cur.z], n3=norm[cur.w];
    uint2 va = *(const uint2*)(Z + (size_t)cur.x*256 + lane*4);
    uint2 vb = *(const uint2*)(Z + (size_t)cur.y*256 + lane*4);
    uint2 vc = *(const uint2*)(Z + (size_t)cur.z*256 + lane*4);
    uint2 vd = *(const uint2*)(Z + (size_t)cur.w*256 + lane*4);
    a0 += fmaxf(bflo(va.x)*sc.x+sh.x,0.f)*n0 + fmaxf(bflo(vb.x)*sc.x+sh.x,0.f)*n1
        + fmaxf(bflo(vc.x)*sc.x+sh.x,0.f)*n2 + fmaxf(bflo(vd.x)*sc.x+sh.x,0.f)*n3;
    a1 += fmaxf(bfhi(va.x)*sc.y+sh.y,0.f)*n0 + fmaxf(bfhi(vb.x)*sc.y+sh.y,0.f)*n1
        + fmaxf(bfhi(vc.x)*sc.y+sh.y,0.f)*n2 + fmaxf(bfhi(vd.x)*sc.y+sh.y,0.f)*n3;
    a2 += fmaxf(bflo(va.y)*sc.z+sh.z,0.f)*n0 + fmaxf(bflo(vb.y)*sc.z+sh.z,0.f)*n1
        + fmaxf(bflo(vc.y)*sc.z+sh.z,0.f)*n2 + fmaxf(bflo(vd.y)*sc.z+sh.z,0.f)*n3;
    a3 += fmaxf(bfhi(va.y)*sc.w+sh.w,0.f)*n0 + fmaxf(bfhi(vb.y)*sc.w+sh.w,0.f)*n1
        + fmaxf(bfhi(vc.y)*sc.w+sh.w,0.f)*n2 + fmaxf(bfhi(vd.y)*sc.w+sh.w,0.f)*n3;
  }
  float nn = norm[node];
  uint2 pkk;
  pkk.x = pk2(a0*nn, a1*nn);
  pkk.y = pk2(a2*nn, a3*nn);
  *(uint2*)(out + (size_t)node*256 + lane*4) = pkk;
}

// final aggregation: X3p rows 64 bf16 (cols 40-63 zero). 8 edges/iter, uint4/lane.
__global__ __launch_bounds__(64) void k_agg64(const unsigned short* __restrict__ X3p,
    const int* __restrict__ rp, const int* __restrict__ esrc,
    const float* __restrict__ norm, const float* __restrict__ b3,
    float* __restrict__ out){
  int node = blockIdx.x, lane = threadIdx.x;
  int s0 = rp[node], s1 = rp[node+1];
  int es = lane >> 3, s = lane & 7;
  float a[8] = {};
  for(int e=s0; e<s1; e+=8){
    int4 A4 = *(const int4*)(esrc+e);
    int4 B4 = *(const int4*)(esrc+e+4);
    int idx = es==0?A4.x: es==1?A4.y: es==2?A4.z: es==3?A4.w:
              es==4?B4.x: es==5?B4.y: es==6?B4.z: B4.w;
    uint4 v = *(const uint4*)(X3p + (size_t)idx*64 + s*8);
    a[0]+=bflo(v.x); a[1]+=bfhi(v.x); a[2]+=bflo(v.y); a[3]+=bfhi(v.y);
    a[4]+=bflo(v.z); a[5]+=bfhi(v.z); a[6]+=bflo(v.w); a[7]+=bfhi(v.w);
  }
  #pragma unroll
  for(int off=8; off<64; off<<=1){
    #pragma unroll
    for(int j=0;j<8;j++) a[j] += __shfl_xor(a[j], off, 64);
  }
  bool act = s < 5;   // cols s*8..s*8+7 < 40
  float nn = norm[node];
  float bv[8] = {};
  if(act){
    float4 t0 = *(const float4*)(b3 + s*8);
    float4 t1 = *(const float4*)(b3 + s*8 + 4);
    bv[0]=t0.x; bv[1]=t0.y; bv[2]=t0.z; bv[3]=t0.w;
    bv[4]=t1.x; bv[5]=t1.y; bv[6]=t1.z; bv[7]=t1.w;
  }
  float v[8];
  float mx = -INFINITY;
  #pragma unroll
  for(int j=0;j<8;j++){
    v[j] = act ? (a[j]*nn + bv[j]) : -INFINITY;
    mx = fmaxf(mx, v[j]);
  }
  #pragma unroll
  for(int off=32; off; off>>=1) mx = fmaxf(mx, __shfl_xor(mx, off, 64));
  float sum = 0.f;
  if(act && es==0){
    #pragma unroll
    for(int j=0;j<8;j++) sum += expf(v[j]-mx);
  }
  #pragma unroll
  for(int off=32; off; off>>=1) sum += __shfl_xor(sum, off, 64);
  float lse = logf(sum);
  if(act && es==0){
    float4 o0, o1;
    o0.x=v[0]-mx-lse; o0.y=v[1]-mx-lse; o0.z=v[2]-mx-lse; o0.w=v[3]-mx-lse;
    o1.x=v[4]-mx-lse; o1.y=v[5]-mx-lse; o1.z=v[6]-mx-lse; o1.w=v[7]-mx-lse;
    *(float4*)(out + (size_t)node*40 + s*8) = o0;
    *(float4*)(out + (size_t)node*40 + s*8 + 4) = o1;
  }
}

// ---------------- MFMA GEMM: C = A*Bt^T + bias (bf16 out) + fused column stats ----------------

__global__ __launch_bounds__(256) void k_mgemm(
    const unsigned short* __restrict__ A, const unsigned short* __restrict__ Bt,
    const float* __restrict__ bias, unsigned short* __restrict__ C,
    float* __restrict__ sums, int M, int K, int Nn){
  __shared__ unsigned short As[128*64];
  __shared__ unsigned short Bs[128*64];
  int nt = Nn >> 7;
  int bm = blockIdx.x / nt, bn = blockIdx.x % nt;
  int m0 = bm*128, n0 = bn*128;
  int tid = threadIdx.x;
  int wave = tid >> 6, lane = tid & 63;
  int wm = (wave>>1)*64, wn = (wave&1)*64;
  int lrow = lane & 15, lq = lane >> 4;
  int srow = lane >> 3;
  int sx = ((lane & 7) ^ srow) * 8;
  f32x4 acc[4][4] = {};
  for(int k0=0; k0<K; k0+=64){
    __syncthreads();
    #pragma unroll
    for(int c4=0;c4<4;c4++){
      int c = wave*4 + c4;
      int grow = c*8 + srow;
      const unsigned short* ga = A + (size_t)(m0+grow)*K + k0 + sx;
      __builtin_amdgcn_global_load_lds((const __attribute__((address_space(1))) void*)ga,
          (__attribute__((address_space(3))) void*)(As + (size_t)c*512), 16, 0, 0);
      const unsigned short* gb = Bt + (size_t)(n0+grow)*K + k0 + sx;
      __builtin_amdgcn_global_load_lds((const __attribute__((address_space(1))) void*)gb,
          (__attribute__((address_space(3))) void*)(Bs + (size_t)c*512), 16, 0, 0);
    }
    __syncthreads();
    #pragma unroll
    for(int kk=0;kk<2;kk++){
      short8 af[4], bf[4];
      #pragma unroll
      for(int i=0;i<4;i++){
        int Ra = wm + i*16 + lrow;
        int ca = (kk*4 + lq) ^ (Ra & 7);
        af[i] = *(const short8*)(As + Ra*64 + ca*8);
        int Rb = wn + i*16 + lrow;
        int cb = (kk*4 + lq) ^ (Rb & 7);
        bf[i] = *(const short8*)(Bs + Rb*64 + cb*8);
      }
      #pragma unroll
      for(int i=0;i<4;i++)
        #pragma unroll
        for(int j=0;j<4;j++)
          acc[i][j] = __builtin_amdgcn_mfma_f32_16x16x32_bf16(af[i], bf[j], acc[i][j], 0, 0, 0);
    }
  }
  // epilogue: write C (bf16) and accumulate column sum/sumsq for BN stats
  #pragma unroll
  for(int j=0;j<4;j++){
    int col = n0 + wn + j*16 + lrow;
    float bj = bias[col];
    float s=0.f, s2=0.f;
    #pragma unroll
    for(int i=0;i<4;i++){
      #pragma unroll
      for(int r=0;r<4;r++){
        int row = m0 + wm + i*16 + lq*4 + r;
        if(row < M){
          float v = acc[i][j][r] + bj;
          s += v; s2 += v*v;
          C[(size_t)row*Nn + col] = f2bf(v);
        }
      }
    }
    s  += __shfl_xor(s, 16, 64);  s  += __shfl_xor(s, 32, 64);
    s2 += __shfl_xor(s2, 16, 64); s2 += __shfl_xor(s2, 32, 64);
    if(lq == 0){
      atomicAdd(&sums[col], s);
      atomicAdd(&sums[256+col], s2);
    }
  }
}

// layer-3: 128x64 tile; A-staging applies BN+ReLU (scsh) on the fly (reg->LDS);
// out X3p bf16 stride 64 (*rownorm). Bt = Wt3 (64 x K).
__global__ __launch_bounds__(256) void k_mgemm3(
    const unsigned short* __restrict__ Zin, const unsigned short* __restrict__ Bt,
    const float* __restrict__ scsh, const float* __restrict__ rownorm,
    unsigned short* __restrict__ X3p, int M, int K){
  __shared__ unsigned short As[128*64];
  __shared__ unsigned short Bs[64*64];
  int m0 = blockIdx.x*128;
  int tid = threadIdx.x;
  int wave = tid >> 6, lane = tid & 63;
  int wm = wave*32;
  int lrow = lane & 15, lq = lane >> 4;
  int srow = lane >> 3;
  int sx = ((lane & 7) ^ srow) * 8;
  f32x4 acc[2][4] = {};
  for(int k0=0; k0<K; k0+=64){
    // prefetch raw A (pre-BN Z2) to regs while previous iter computes
    uint4 raw[4];
    #pragma unroll
    for(int c4=0;c4<4;c4++){
      int c = wave*4 + c4;
      int grow = c*8 + srow;
      raw[c4] = *(const uint4*)(Zin + (size_t)(m0+grow)*K + k0 + sx);
    }
    float4 sc0 = *(const float4*)(scsh + k0 + sx);
    float4 sc1 = *(const float4*)(scsh + k0 + sx + 4);
    float4 sh0 = *(const float4*)(scsh + 256 + k0 + sx);
    float4 sh1 = *(const float4*)(scsh + 256 + k0 + sx + 4);
    __syncthreads();                 // previous iter's LDS reads done
    #pragma unroll
    for(int c4=0;c4<4;c4++){
      int c = wave*4 + c4;
      uint4 w;
      w.x = pk2(fmaxf(bflo(raw[c4].x)*sc0.x+sh0.x,0.f), fmaxf(bfhi(raw[c4].x)*sc0.y+sh0.y,0.f));
      w.y = pk2(fmaxf(bflo(raw[c4].y)*sc0.z+sh0.z,0.f), fmaxf(bfhi(raw[c4].y)*sc0.w+sh0.w,0.f));
      w.z = pk2(fmaxf(bflo(raw[c4].z)*sc1.x+sh1.x,0.f), fmaxf(bfhi(raw[c4].z)*sc1.y+sh1.y,0.f));
      w.w = pk2(fmaxf(bflo(raw[c4].w)*sc1.z+sh1.z,0.f), fmaxf(bfhi(raw[c4].w)*sc1.w+sh1.w,0.f));
      *(uint4*)(As + (size_t)c*512 + (size_t)lane*8) = w;
    }
    #pragma unroll
    for(int c4=0;c4<2;c4++){
      int c = wave*2 + c4;
      int grow = c*8 + srow;            // 0..63
      const unsigned short* gb = Bt + (size_t)grow*K + k0 + sx;
      __builtin_amdgcn_global_load_lds((const __attribute__((address_space(1))) void*)gb,
          (__attribute__((address_space(3))) void*)(Bs + (size_t)c*512), 16, 0, 0);
    }
    __syncthreads();
    #pragma unroll
    for(int kk=0;kk<2;kk++){
      short8 af[2], bf[4];
      #pragma unroll
      for(int i=0;i<2;i++){
        int Ra = wm + i*16 + lrow;
        int ca = (kk*4 + lq) ^ (Ra & 7);
        af[i] = *(const short8*)(As + Ra*64 + ca*8);
      }
      #pragma unroll
      for(int j=0;j<4;j++){
        int Rb = j*16 + lrow;
        int cb = (kk*4 + lq) ^ (Rb & 7);
        bf[j] = *(const short8*)(Bs + Rb*64 + cb*8);
      }
      #pragma unroll
      for(int i=0;i<2;i++)
        #pragma unroll
        for(int j=0;j<4;j++)
          acc[i][j] = __builtin_amdgcn_mfma_f32_16x16x32_bf16(af[i], bf[j], acc[i][j], 0, 0, 0);
    }
  }
  #pragma unroll
  for(int j=0;j<4;j++){
    int col = j*16 + lrow;
    #pragma unroll
    for(int i=0;i<2;i++){
      #pragma unroll
      for(int r=0;r<4;r++){
        int row = m0 + wm + i*16 + lq*4 + r;
        if(row < M) X3p[(size_t)row*64 + col] = f2bf(acc[i][j][r] * rownorm[row]);
      }
    }
  }
}

// ---------------- launch ----------------

extern "C" void kernel_launch(void* const* d_in, const int* in_sizes, int n_in,
                              void* d_out, int out_size, void* d_ws, size_t ws_size,
                              hipStream_t stream){
  const float* x   = (const float*)d_in[0];
  const int*   src = (const int*)d_in[1];
  const int*   dst = (const int*)d_in[2];
  const float* W1  = (const float*)d_in[3];
  const float* b1  = (const float*)d_in[4];
  const float* g1  = (const float*)d_in[5];
  const float* be1 = (const float*)d_in[6];
  const float* W2  = (const float*)d_in[7];
  const float* b2  = (const float*)d_in[8];
  const float* g2  = (const float*)d_in[9];
  const float* be2 = (const float*)d_in[10];
  const float* W3  = (const float*)d_in[11];
  const float* b3  = (const float*)d_in[12];
  float* out = (float*)d_out;
  const int N = NN;
  const int E = in_sizes[1];
  const int Eh = E >> 1;          // bidirected: second half mirrors the first

  char* p = (char*)d_ws;
  size_t off = 0;
  auto alloc = [&](size_t bytes)->void*{
    void* r = p + off;
    off += (bytes + 511) & ~(size_t)511;
    return r;
  };
  // Footprint ~183.8 MB — under the ~229 MB known-good high-water mark.
  // (ws crash forensics: 270 MB crash / 219 pass / 229 pass / 235 crash.)
  int*   cnt   = (int*)  alloc((size_t)N*4);
  int*   fill  = (int*)  alloc((size_t)N*4);
  float* sums1 = (float*)alloc(2048);
  float* sums2 = (float*)alloc(2048);
  size_t zero_bytes = off;                       // cnt|fill|sums zeroed each call
  int*   rp    = (int*)  alloc((size_t)(N+1)*4);
  float* norm  = (float*)alloc((size_t)(N+1)*4);
  float* scsh1 = (float*)alloc(2048);
  float* scsh2 = (float*)alloc(2048);
  unsigned short* Wt1 = (unsigned short*)alloc((size_t)256*128*2);
  unsigned short* Wt2 = (unsigned short*)alloc((size_t)256*256*2);
  unsigned short* Wt3 = (unsigned short*)alloc((size_t)64*256*2);
  int*   esrc  = (int*)  alloc((size_t)(E + 7*N + 16)*4);            // pad-8 CSR
  unsigned short* Hx  = (unsigned short*)alloc((size_t)(N+1)*128*2); // x*norm + zero row
  unsigned short* M1  = (unsigned short*)alloc((size_t)N*128*2);     // agg128 out
  unsigned short* Mb2 = (unsigned short*)alloc((size_t)N*256*2);     // agg256f out
  unsigned short* Z   = (unsigned short*)alloc((size_t)(N+1)*256*2); // mgemm out + zero row
  unsigned short* X3p = (unsigned short*)alloc((size_t)(N+1)*64*2);  // layer-3 proj (64-col)
  (void)ws_size; (void)n_in; (void)out_size;

  hipMemsetAsync(d_ws, 0, zero_bytes, stream);

  k_hist   <<<(E+255)/256,256,0,stream>>>(dst, cnt, E);
  k_norm   <<<(N+256)/256,256,0,stream>>>(cnt, norm, N);
  k_scan   <<<1,1024,0,stream>>>(cnt, rp, N);
  hipMemcpyAsync(fill, rp, (size_t)N*4, hipMemcpyDeviceToDevice, stream);
  k_scatter2<<<(Eh+255)/256,256,0,stream>>>(src, dst, fill, esrc, Eh);
  k_pad    <<<(N+255)/256,256,0,stream>>>(fill, rp, esrc, N);
  k_zeropad<<<1,256,0,stream>>>(Hx, X3p, Z);
  k_wprep  <<<(128*256+255)/256,256,0,stream>>>(W1, Wt1, 128, 256);
  k_wprep  <<<(256*256+255)/256,256,0,stream>>>(W2, Wt2, 256, 256);
  k_wprep3 <<<(64*256+255)/256,256,0,stream>>>(W3, Wt3);

  // layer 1: Hx = x*norm -> agg128*norm -> MFMA @W1+b1 (+stats) -> Z1(bf16)
  k_scale_x<<<(N*128+255)/256,256,0,stream>>>(x, norm, Hx, N*128);
  k_agg128 <<<N,64,0,stream>>>(Hx, rp, esrc, norm, M1);
  k_mgemm  <<<((N+127)/128)*2,256,0,stream>>>(M1, Wt1, b1, Z, sums1, N, 128, 256);
  k_bnfin  <<<1,256,0,stream>>>(sums1, g1, be1, scsh1, N);

  // layer 2: agg256 fused BN+ReLU+norm[src] on Z1 -> MFMA @W2+b2 (+stats) -> Z2
  k_agg256f<<<N,64,0,stream>>>(Z, rp, esrc, norm, scsh1, Mb2);
  k_mgemm  <<<((N+127)/128)*2,256,0,stream>>>(Mb2, Wt2, b2, Z, sums2, N, 256, 256);
  k_bnfin  <<<1,256,0,stream>>>(sums2, g2, be2, scsh2, N);

  // layer 3: mgemm3 applies BN+ReLU to Z2 in staging, X3p = (relu(bn(Z2))@W3p)*norm
  k_mgemm3 <<<(N+127)/128,256,0,stream>>>(Z, Wt3, scsh2, norm, X3p, N, 256);
  k_agg64  <<<N,64,0,stream>>>(X3p, rp, esrc, norm, b3, out);
}

// Round 9
// 1240.507 us; speedup vs baseline: 1.0976x; 1.0180x over previous
//
#include <hip/hip_runtime.h>
#include <cstdint>
#include <cstddef>

#define NN 100000
#define BN_EPS 1e-5f

typedef __attribute__((ext_vector_type(8))) short short8;
typedef __attribute__((ext_vector_type(4))) float f32x4;

static __device__ __forceinline__ float bflo(unsigned u){ return __uint_as_float(u<<16); }
static __device__ __forceinline__ float bfhi(unsigned u){ return __uint_as_float(u & 0xFFFF0000u); }
static __device__ __forceinline__ unsigned short f2bf(float f){
  unsigned u = __float_as_uint(f);
  u += 0x7FFFu + ((u>>16)&1u);   // round-to-nearest-even
  return (unsigned short)(u>>16);
}
static __device__ __forceinline__ unsigned pk2(float a, float b){
  return (unsigned)f2bf(a) | ((unsigned)f2bf(b) << 16);
}

// ---------------- graph prep ----------------

__global__ void k_hist(const int* __restrict__ dst, int* __restrict__ cnt, int E){
  int e = blockIdx.x*blockDim.x + threadIdx.x;
  if(e<E) atomicAdd(&cnt[dst[e]], 1);
}

// norm over N+1: norm[NN] = 0 (zero row / pad-edge killer)
__global__ void k_norm(const int* __restrict__ cnt, float* __restrict__ norm, int n){
  int i = blockIdx.x*blockDim.x + threadIdx.x;
  if(i<=n) norm[i] = (i==n) ? 0.f : rsqrtf(fmaxf((float)cnt[i], 1.0f));
}

// exclusive scan over counts padded to multiple of 8
__global__ __launch_bounds__(1024) void k_scan(const int* __restrict__ cnt, int* __restrict__ rp, int n){
  __shared__ int sm[1024];
  int t = threadIdx.x;
  int chunk = (n + 1023)/1024;
  int lo = t*chunk, hi = min(lo+chunk, n);
  int s=0;
  for(int i=lo;i<hi;i++) s += (cnt[i]+7)&~7;
  sm[t]=s; __syncthreads();
  for(int off=1; off<1024; off<<=1){
    int v = (t>=off)? sm[t-off] : 0;
    __syncthreads();
    sm[t]+=v;
    __syncthreads();
  }
  int run = sm[t]-s;
  for(int i=lo;i<hi;i++){ rp[i]=run; run+=(cnt[i]+7)&~7; }
  if(t==1023) rp[n]=sm[1023];
}

// full-E scatter, 4 edges/thread: int4 loads, 4 independent returned atomics in
// flight (MLP=4), then 4 scatter stores. fill[] pre-loaded with rp[] (d2d copy).
__global__ void k_scatter4(const int* __restrict__ src, const int* __restrict__ dst,
                           int* __restrict__ fill, int* __restrict__ esrc, int E){
  int base = (blockIdx.x*blockDim.x + threadIdx.x)*4;
  if(base+3 < E){
    int4 s4 = *(const int4*)(src+base);
    int4 d4 = *(const int4*)(dst+base);
    int p0 = atomicAdd(&fill[d4.x], 1);
    int p1 = atomicAdd(&fill[d4.y], 1);
    int p2 = atomicAdd(&fill[d4.z], 1);
    int p3 = atomicAdd(&fill[d4.w], 1);
    esrc[p0]=s4.x; esrc[p1]=s4.y; esrc[p2]=s4.z; esrc[p3]=s4.w;
  }else{
    for(int e=base; e<E; e++){
      int pos = atomicAdd(&fill[dst[e]], 1);
      esrc[pos] = src[e];
    }
  }
}

// pad slots [fill[i], rp[i+1]) with NN (fill[i] == rp[i]+cnt[i] after scatter)
__global__ void k_pad(const int* __restrict__ fill, const int* __restrict__ rp,
                      int* __restrict__ esrc, int n){
  int i = blockIdx.x*blockDim.x + threadIdx.x;
  if(i<n){
    int base = fill[i], end = rp[i+1];
    for(int j=base;j<end;j++) esrc[j]=NN;
  }
}

// zero pad rows: Hx row NN (128), X3p row NN (64), Z row NN (256)
__global__ void k_zeropad(unsigned short* __restrict__ Hx, unsigned short* __restrict__ X3p,
                          unsigned short* __restrict__ Z){
  int t = threadIdx.x;
  if(t<128) Hx[(size_t)NN*128 + t] = 0;
  if(t<64)  X3p[(size_t)NN*64 + t] = 0;
  Z[(size_t)NN*256 + t] = 0;
}

// ---------------- elementwise / weight prep ----------------

__global__ void k_scale_x(const float* __restrict__ x, const float* __restrict__ norm,
                          unsigned short* __restrict__ H, int total){
  int i = blockIdx.x*blockDim.x + threadIdx.x;
  if(i<total) H[i] = f2bf(x[i] * norm[i>>7]);   // 128 feats/row
}

// W (K x N fp32) -> Wt (N x K bf16)
__global__ void k_wprep(const float* __restrict__ W, unsigned short* __restrict__ Wt, int K, int N){
  int i = blockIdx.x*blockDim.x + threadIdx.x;
  if(i < K*N){
    int k = i / N, n = i - k*N;
    Wt[(size_t)n*K + k] = f2bf(W[i]);
  }
}

// W3 (256 x 40 fp32) -> Wt3 (64 x 256 bf16), rows >= 40 zero
__global__ void k_wprep3(const float* __restrict__ W3, unsigned short* __restrict__ Wt){
  int i = blockIdx.x*blockDim.x + threadIdx.x;
  if(i < 64*256){
    int n = i >> 8, k = i & 255;
    Wt[i] = (n < 40) ? f2bf(W3[(size_t)k*40 + n]) : (unsigned short)0;
  }
}

// ---------------- BN finalize ----------------

__global__ void k_bnfin(const float* __restrict__ sums, const float* __restrict__ gamma,
                        const float* __restrict__ beta, float* __restrict__ scsh, int M){
  int c = threadIdx.x;
  float mean = sums[c]/(float)M;
  float var  = sums[256+c]/(float)M - mean*mean;
  float sc = gamma[c]*rsqrtf(var + BN_EPS);
  scsh[c] = sc;
  scsh[256+c] = beta[c] - mean*sc;
}

// ---------------- aggregation (wave per node, padded CSR) ----------------

__global__ __launch_bounds__(64) void k_agg128(const unsigned short* __restrict__ H,
    const int* __restrict__ rp, const int* __restrict__ esrc,
    const float* __restrict__ norm, unsigned short* __restrict__ out){
  int node = blockIdx.x, lane = threadIdx.x;
  int s0 = rp[node], s1 = rp[node+1];
  float a0=0.f, a1=0.f;
  for(int e=s0; e<s1; e+=4){
    int4 cur = *(const int4*)(esrc+e);
    unsigned v0 = *(const unsigned*)(H + (size_t)cur.x*128 + lane*2);
    unsigned v1 = *(const unsigned*)(H + (size_t)cur.y*128 + lane*2);
    unsigned v2 = *(const unsigned*)(H + (size_t)cur.z*128 + lane*2);
    unsigned v3 = *(const unsigned*)(H + (size_t)cur.w*128 + lane*2);
    a0 += bflo(v0)+bflo(v1)+bflo(v2)+bflo(v3);
    a1 += bfhi(v0)+bfhi(v1)+bfhi(v2)+bfhi(v3);
  }
  float nn = norm[node];
  *(unsigned*)(out + (size_t)node*128 + lane*2) = pk2(a0*nn, a1*nn);
}

// layer-2 aggregation with BN+ReLU+norm[src] fused into the gather.
// reads raw Z1 (bf16, pre-BN, zero row NN); lane owns cols lane*4..lane*4+3.
__global__ __launch_bounds__(64) void k_agg256f(const unsigned short* __restrict__ Z,
    const int* __restrict__ rp, const int* __restrict__ esrc,
    const float* __restrict__ norm, const float* __restrict__ scsh,
    unsigned short* __restrict__ out){
  int node = blockIdx.x, lane = threadIdx.x;
  float4 sc = *(const float4*)(scsh + lane*4);
  float4 sh = *(const float4*)(scsh + 256 + lane*4);
  int s0 = rp[node], s1 = rp[node+1];
  float a0=0.f,a1=0.f,a2=0.f,a3=0.f;
  for(int e=s0; e<s1; e+=4){
    int4 cur = *(const int4*)(esrc+e);
    float n0=norm[cur.x], n1=norm[cur.y], n2=norm[cur.z], n3=norm[cur.w];
    uint2 va = *(const uint2*)(Z + (size_t)cur.x*256 + lane*4);
    uint2 vb = *(const uint2*)(Z + (size_t)cur.y*256 + lane*4);
    uint2 vc = *(const uint2*)(Z + (size_t)cur.z*256 + lane*4);
    uint2 vd = *(const uint2*)(Z + (size_t)cur.w*256 + lane*4);
    a0 += fmaxf(bflo(va.x)*sc.x+sh.x,0.f)*n0 + fmaxf(bflo(vb.x)*sc.x+sh.x,0.f)*n1
        + fmaxf(bflo(vc.x)*sc.x+sh.x,0.f)*n2 + fmaxf(bflo(vd.x)*sc.x+sh.x,0.f)*n3;
    a1 += fmaxf(bfhi(va.x)*sc.y+sh.y,0.f)*n0 + fmaxf(bfhi(vb.x)*sc.y+sh.y,0.f)*n1
        + fmaxf(bfhi(vc.x)*sc.y+sh.y,0.f)*n2 + fmaxf(bfhi(vd.x)*sc.y+sh.y,0.f)*n3;
    a2 += fmaxf(bflo(va.y)*sc.z+sh.z,0.f)*n0 + fmaxf(bflo(vb.y)*sc.z+sh.z,0.f)*n1
        + fmaxf(bflo(vc.y)*sc.z+sh.z,0.f)*n2 + fmaxf(bflo(vd.y)*sc.z+sh.z,0.f)*n3;
    a3 += fmaxf(bfhi(va.y)*sc.w+sh.w,0.f)*n0 + fmaxf(bfhi(vb.y)*sc.w+sh.w,0.f)*n1
        + fmaxf(bfhi(vc.y)*sc.w+sh.w,0.f)*n2 + fmaxf(bfhi(vd.y)*sc.w+sh.w,0.f)*n3;
  }
  float nn = norm[node];
  uint2 pkk;
  pkk.x = pk2(a0*nn, a1*nn);
  pkk.y = pk2(a2*nn, a3*nn);
  *(uint2*)(out + (size_t)node*256 + lane*4) = pkk;
}

// final aggregation: X3p rows 64 bf16 (cols 40-63 zero). 8 edges/iter, uint4/lane.
__global__ __launch_bounds__(64) void k_agg64(const unsigned short* __restrict__ X3p,
    const int* __restrict__ rp, const int* __restrict__ esrc,
    const float* __restrict__ norm, const float* __restrict__ b3,
    float* __restrict__ out){
  int node = blockIdx.x, lane = threadIdx.x;
  int s0 = rp[node], s1 = rp[node+1];
  int es = lane >> 3, s = lane & 7;
  float a[8] = {};
  for(int e=s0; e<s1; e+=8){
    int4 A4 = *(const int4*)(esrc+e);
    int4 B4 = *(const int4*)(esrc+e+4);
    int idx = es==0?A4.x: es==1?A4.y: es==2?A4.z: es==3?A4.w:
              es==4?B4.x: es==5?B4.y: es==6?B4.z: B4.w;
    uint4 v = *(const uint4*)(X3p + (size_t)idx*64 + s*8);
    a[0]+=bflo(v.x); a[1]+=bfhi(v.x); a[2]+=bflo(v.y); a[3]+=bfhi(v.y);
    a[4]+=bflo(v.z); a[5]+=bfhi(v.z); a[6]+=bflo(v.w); a[7]+=bfhi(v.w);
  }
  #pragma unroll
  for(int off=8; off<64; off<<=1){
    #pragma unroll
    for(int j=0;j<8;j++) a[j] += __shfl_xor(a[j], off, 64);
  }
  bool act = s < 5;   // cols s*8..s*8+7 < 40
  float nn = norm[node];
  float bv[8] = {};
  if(act){
    float4 t0 = *(const float4*)(b3 + s*8);
    float4 t1 = *(const float4*)(b3 + s*8 + 4);
    bv[0]=t0.x; bv[1]=t0.y; bv[2]=t0.z; bv[3]=t0.w;
    bv[4]=t1.x; bv[5]=t1.y; bv[6]=t1.z; bv[7]=t1.w;
  }
  float v[8];
  float mx = -INFINITY;
  #pragma unroll
  for(int j=0;j<8;j++){
    v[j] = act ? (a[j]*nn + bv[j]) : -INFINITY;
    mx = fmaxf(mx, v[j]);
  }
  #pragma unroll
  for(int off=32; off; off>>=1) mx = fmaxf(mx, __shfl_xor(mx, off, 64));
  float sum = 0.f;
  if(act && es==0){
    #pragma unroll
    for(int j=0;j<8;j++) sum += expf(v[j]-mx);
  }
  #pragma unroll
  for(int off=32; off; off>>=1) sum += __shfl_xor(sum, off, 64);
  float lse = logf(sum);
  if(act && es==0){
    float4 o0, o1;
    o0.x=v[0]-mx-lse; o0.y=v[1]-mx-lse; o0.z=v[2]-mx-lse; o0.w=v[3]-mx-lse;
    o1.x=v[4]-mx-lse; o1.y=v[5]-mx-lse; o1.z=v[6]-mx-lse; o1.w=v[7]-mx-lse;
    *(float4*)(out + (size_t)node*40 + s*8) = o0;
    *(float4*)(out + (size_t)node*40 + s*8 + 4) = o1;
  }
}

// ---------------- MFMA GEMM: C = A*Bt^T + bias (bf16 out) + fused column stats ----------------

__global__ __launch_bounds__(256) void k_mgemm(
    const unsigned short* __restrict__ A, const unsigned short* __restrict__ Bt,
    const float* __restrict__ bias, unsigned short* __restrict__ C,
    float* __restrict__ sums, int M, int K, int Nn){
  __shared__ unsigned short As[128*64];
  __shared__ unsigned short Bs[128*64];
  int nt = Nn >> 7;
  int bm = blockIdx.x / nt, bn = blockIdx.x % nt;
  int m0 = bm*128, n0 = bn*128;
  int tid = threadIdx.x;
  int wave = tid >> 6, lane = tid & 63;
  int wm = (wave>>1)*64, wn = (wave&1)*64;
  int lrow = lane & 15, lq = lane >> 4;
  int srow = lane >> 3;
  int sx = ((lane & 7) ^ srow) * 8;
  f32x4 acc[4][4] = {};
  for(int k0=0; k0<K; k0+=64){
    __syncthreads();
    #pragma unroll
    for(int c4=0;c4<4;c4++){
      int c = wave*4 + c4;
      int grow = c*8 + srow;
      const unsigned short* ga = A + (size_t)(m0+grow)*K + k0 + sx;
      __builtin_amdgcn_global_load_lds((const __attribute__((address_space(1))) void*)ga,
          (__attribute__((address_space(3))) void*)(As + (size_t)c*512), 16, 0, 0);
      const unsigned short* gb = Bt + (size_t)(n0+grow)*K + k0 + sx;
      __builtin_amdgcn_global_load_lds((const __attribute__((address_space(1))) void*)gb,
          (__attribute__((address_space(3))) void*)(Bs + (size_t)c*512), 16, 0, 0);
    }
    __syncthreads();
    #pragma unroll
    for(int kk=0;kk<2;kk++){
      short8 af[4], bf[4];
      #pragma unroll
      for(int i=0;i<4;i++){
        int Ra = wm + i*16 + lrow;
        int ca = (kk*4 + lq) ^ (Ra & 7);
        af[i] = *(const short8*)(As + Ra*64 + ca*8);
        int Rb = wn + i*16 + lrow;
        int cb = (kk*4 + lq) ^ (Rb & 7);
        bf[i] = *(const short8*)(Bs + Rb*64 + cb*8);
      }
      #pragma unroll
      for(int i=0;i<4;i++)
        #pragma unroll
        for(int j=0;j<4;j++)
          acc[i][j] = __builtin_amdgcn_mfma_f32_16x16x32_bf16(af[i], bf[j], acc[i][j], 0, 0, 0);
    }
  }
  // epilogue: write C (bf16) and accumulate column sum/sumsq for BN stats
  #pragma unroll
  for(int j=0;j<4;j++){
    int col = n0 + wn + j*16 + lrow;
    float bj = bias[col];
    float s=0.f, s2=0.f;
    #pragma unroll
    for(int i=0;i<4;i++){
      #pragma unroll
      for(int r=0;r<4;r++){
        int row = m0 + wm + i*16 + lq*4 + r;
        if(row < M){
          float v = acc[i][j][r] + bj;
          s += v; s2 += v*v;
          C[(size_t)row*Nn + col] = f2bf(v);
        }
      }
    }
    s  += __shfl_xor(s, 16, 64);  s  += __shfl_xor(s, 32, 64);
    s2 += __shfl_xor(s2, 16, 64); s2 += __shfl_xor(s2, 32, 64);
    if(lq == 0){
      atomicAdd(&sums[col], s);
      atomicAdd(&sums[256+col], s2);
    }
  }
}

// layer-3: 128x64 tile; A-staging applies BN+ReLU (scsh) on the fly (reg->LDS);
// out X3p bf16 stride 64 (*rownorm). Bt = Wt3 (64 x K).
__global__ __launch_bounds__(256) void k_mgemm3(
    const unsigned short* __restrict__ Zin, const unsigned short* __restrict__ Bt,
    const float* __restrict__ scsh, const float* __restrict__ rownorm,
    unsigned short* __restrict__ X3p, int M, int K){
  __shared__ unsigned short As[128*64];
  __shared__ unsigned short Bs[64*64];
  int m0 = blockIdx.x*128;
  int tid = threadIdx.x;
  int wave = tid >> 6, lane = tid & 63;
  int wm = wave*32;
  int lrow = lane & 15, lq = lane >> 4;
  int srow = lane >> 3;
  int sx = ((lane & 7) ^ srow) * 8;
  f32x4 acc[2][4] = {};
  for(int k0=0; k0<K; k0+=64){
    // prefetch raw A (pre-BN Z2) to regs while previous iter computes
    uint4 raw[4];
    #pragma unroll
    for(int c4=0;c4<4;c4++){
      int c = wave*4 + c4;
      int grow = c*8 + srow;
      raw[c4] = *(const uint4*)(Zin + (size_t)(m0+grow)*K + k0 + sx);
    }
    float4 sc0 = *(const float4*)(scsh + k0 + sx);
    float4 sc1 = *(const float4*)(scsh + k0 + sx + 4);
    float4 sh0 = *(const float4*)(scsh + 256 + k0 + sx);
    float4 sh1 = *(const float4*)(scsh + 256 + k0 + sx + 4);
    __syncthreads();                 // previous iter's LDS reads done
    #pragma unroll
    for(int c4=0;c4<4;c4++){
      int c = wave*4 + c4;
      uint4 w;
      w.x = pk2(fmaxf(bflo(raw[c4].x)*sc0.x+sh0.x,0.f), fmaxf(bfhi(raw[c4].x)*sc0.y+sh0.y,0.f));
      w.y = pk2(fmaxf(bflo(raw[c4].y)*sc0.z+sh0.z,0.f), fmaxf(bfhi(raw[c4].y)*sc0.w+sh0.w,0.f));
      w.z = pk2(fmaxf(bflo(raw[c4].z)*sc1.x+sh1.x,0.f), fmaxf(bfhi(raw[c4].z)*sc1.y+sh1.y,0.f));
      w.w = pk2(fmaxf(bflo(raw[c4].w)*sc1.z+sh1.z,0.f), fmaxf(bfhi(raw[c4].w)*sc1.w+sh1.w,0.f));
      *(uint4*)(As + (size_t)c*512 + (size_t)lane*8) = w;
    }
    #pragma unroll
    for(int c4=0;c4<2;c4++){
      int c = wave*2 + c4;
      int grow = c*8 + srow;            // 0..63
      const unsigned short* gb = Bt + (size_t)grow*K + k0 + sx;
      __builtin_amdgcn_global_load_lds((const __attribute__((address_space(1))) void*)gb,
          (__attribute__((address_space(3))) void*)(Bs + (size_t)c*512), 16, 0, 0);
    }
    __syncthreads();
    #pragma unroll
    for(int kk=0;kk<2;kk++){
      short8 af[2], bf[4];
      #pragma unroll
      for(int i=0;i<2;i++){
        int Ra = wm + i*16 + lrow;
        int ca = (kk*4 + lq) ^ (Ra & 7);
        af[i] = *(const short8*)(As + Ra*64 + ca*8);
      }
      #pragma unroll
      for(int j=0;j<4;j++){
        int Rb = j*16 + lrow;
        int cb = (kk*4 + lq) ^ (Rb & 7);
        bf[j] = *(const short8*)(Bs + Rb*64 + cb*8);
      }
      #pragma unroll
      for(int i=0;i<2;i++)
        #pragma unroll
        for(int j=0;j<4;j++)
          acc[i][j] = __builtin_amdgcn_mfma_f32_16x16x32_bf16(af[i], bf[j], acc[i][j], 0, 0, 0);
    }
  }
  #pragma unroll
  for(int j=0;j<4;j++){
    int col = j*16 + lrow;
    #pragma unroll
    for(int i=0;i<2;i++){
      #pragma unroll
      for(int r=0;r<4;r++){
        int row = m0 + wm + i*16 + lq*4 + r;
        if(row < M) X3p[(size_t)row*64 + col] = f2bf(acc[i][j][r] * rownorm[row]);
      }
    }
  }
}

// ---------------- launch ----------------

extern "C" void kernel_launch(void* const* d_in, const int* in_sizes, int n_in,
                              void* d_out, int out_size, void* d_ws, size_t ws_size,
                              hipStream_t stream){
  const float* x   = (const float*)d_in[0];
  const int*   src = (const int*)d_in[1];
  const int*   dst = (const int*)d_in[2];
  const float* W1  = (const float*)d_in[3];
  const float* b1  = (const float*)d_in[4];
  const float* g1  = (const float*)d_in[5];
  const float* be1 = (const float*)d_in[6];
  const float* W2  = (const float*)d_in[7];
  const float* b2  = (const float*)d_in[8];
  const float* g2  = (const float*)d_in[9];
  const float* be2 = (const float*)d_in[10];
  const float* W3  = (const float*)d_in[11];
  const float* b3  = (const float*)d_in[12];
  float* out = (float*)d_out;
  const int N = NN;
  const int E = in_sizes[1];

  char* p = (char*)d_ws;
  size_t off = 0;
  auto alloc = [&](size_t bytes)->void*{
    void* r = p + off;
    off += (bytes + 511) & ~(size_t)511;
    return r;
  };
  // Footprint ~183.8 MB — under the ~229 MB known-good high-water mark.
  // (ws crash forensics: 270 MB crash / 219 pass / 229 pass / 235 crash.)
  int*   cnt   = (int*)  alloc((size_t)N*4);
  int*   fill  = (int*)  alloc((size_t)N*4);
  float* sums1 = (float*)alloc(2048);
  float* sums2 = (float*)alloc(2048);
  size_t zero_bytes = off;                       // cnt|fill|sums zeroed each call
  int*   rp    = (int*)  alloc((size_t)(N+1)*4);
  float* norm  = (float*)alloc((size_t)(N+1)*4);
  float* scsh1 = (float*)alloc(2048);
  float* scsh2 = (float*)alloc(2048);
  unsigned short* Wt1 = (unsigned short*)alloc((size_t)256*128*2);
  unsigned short* Wt2 = (unsigned short*)alloc((size_t)256*256*2);
  unsigned short* Wt3 = (unsigned short*)alloc((size_t)64*256*2);
  int*   esrc  = (int*)  alloc((size_t)(E + 7*N + 16)*4);            // pad-8 CSR
  unsigned short* Hx  = (unsigned short*)alloc((size_t)(N+1)*128*2); // x*norm + zero row
  unsigned short* M1  = (unsigned short*)alloc((size_t)N*128*2);     // agg128 out
  unsigned short* Mb2 = (unsigned short*)alloc((size_t)N*256*2);     // agg256f out
  unsigned short* Z   = (unsigned short*)alloc((size_t)(N+1)*256*2); // mgemm out + zero row
  unsigned short* X3p = (unsigned short*)alloc((size_t)(N+1)*64*2);  // layer-3 proj (64-col)
  (void)ws_size; (void)n_in; (void)out_size;

  hipMemsetAsync(d_ws, 0, zero_bytes, stream);

  k_hist   <<<(E+255)/256,256,0,stream>>>(dst, cnt, E);
  k_norm   <<<(N+256)/256,256,0,stream>>>(cnt, norm, N);
  k_scan   <<<1,1024,0,stream>>>(cnt, rp, N);
  hipMemcpyAsync(fill, rp, (size_t)N*4, hipMemcpyDeviceToDevice, stream);
  k_scatter4<<<(E/4+255)/256,256,0,stream>>>(src, dst, fill, esrc, E);
  k_pad    <<<(N+255)/256,256,0,stream>>>(fill, rp, esrc, N);
  k_zeropad<<<1,256,0,stream>>>(Hx, X3p, Z);
  k_wprep  <<<(128*256+255)/256,256,0,stream>>>(W1, Wt1, 128, 256);
  k_wprep  <<<(256*256+255)/256,256,0,stream>>>(W2, Wt2, 256, 256);
  k_wprep3 <<<(64*256+255)/256,256,0,stream>>>(W3, Wt3);

  // layer 1: Hx = x*norm -> agg128*norm -> MFMA @W1+b1 (+stats) -> Z1(bf16)
  k_scale_x<<<(N*128+255)/256,256,0,stream>>>(x, norm, Hx, N*128);
  k_agg128 <<<N,64,0,stream>>>(Hx, rp, esrc, norm, M1);
  k_mgemm  <<<((N+127)/128)*2,256,0,stream>>>(M1, Wt1, b1, Z, sums1, N, 128, 256);
  k_bnfin  <<<1,256,0,stream>>>(sums1, g1, be1, scsh1, N);

  // layer 2: agg256 fused BN+ReLU+norm[src] on Z1 -> MFMA @W2+b2 (+stats) -> Z2
  k_agg256f<<<N,64,0,stream>>>(Z, rp, esrc, norm, scsh1, Mb2);
  k_mgemm  <<<((N+127)/128)*2,256,0,stream>>>(Mb2, Wt2, b2, Z, sums2, N, 256, 256);
  k_bnfin  <<<1,256,0,stream>>>(sums2, g2, be2, scsh2, N);

  // layer 3: mgemm3 applies BN+ReLU to Z2 in staging, X3p = (relu(bn(Z2))@W3p)*norm
  k_mgemm3 <<<(N+127)/128,256,0,stream>>>(Z, Wt3, scsh2, norm, X3p, N, 256);
  k_agg64  <<<N,64,0,stream>>>(X3p, rp, esrc, norm, b3, out);
}